// Round 1
// baseline (308.238 us; speedup 1.0000x reference)
//
#include <hip/hip_runtime.h>

// Problem constants (from reference)
constexpr int EMB_DIM = 300;
constexpr int HIDDEN  = 256;
constexpr int OUT_DIM = 3;
constexpr int SEQ     = 128;

// ---------------------------------------------------------------------------
// Kernel 1: embedding gather + mean pool.  One block per sample (256 thr).
// Thread t accumulates dims {t, t+256} over the 128 tokens; row reads are
// coalesced (300 contiguous floats split across the block).
// ---------------------------------------------------------------------------
__global__ __launch_bounds__(256) void pool_kernel(
    const int* __restrict__ ids, const float* __restrict__ emb,
    float* __restrict__ x) {
  const int b = blockIdx.x;
  const int t = threadIdx.x;

  __shared__ int sid[SEQ];
  if (t < SEQ) sid[t] = ids[(size_t)b * SEQ + t];
  __syncthreads();

  float acc0 = 0.f, acc1 = 0.f;
#pragma unroll 4
  for (int s = 0; s < SEQ; ++s) {
    const float* __restrict__ r = emb + (size_t)sid[s] * EMB_DIM;
    acc0 += r[t];
    if (t < EMB_DIM - 256) acc1 += r[t + 256];
  }
  const float scale = 1.0f / (float)SEQ;
  x[(size_t)b * EMB_DIM + t] = acc0 * scale;
  if (t < EMB_DIM - 256) x[(size_t)b * EMB_DIM + t + 256] = acc1 * scale;
}

// ---------------------------------------------------------------------------
// Kernel 2: routed 2-layer MLP.  One block per sample (256 thr).
// Layer1: thread j computes h[j] = relu(b1[a][j] + sum_d x[d]*W1[a][d][j]).
//   W1 reads are coalesced across j; x[d] is an LDS broadcast (conflict-free).
// Layer2: per-thread partials h[j]*W2[a][j][k], wave shuffle reduce + LDS.
// Only the sample's own aspect is computed (reference computes all 8, selects).
// ---------------------------------------------------------------------------
__global__ __launch_bounds__(256) void mlp_kernel(
    const float* __restrict__ x, const int* __restrict__ aspect,
    const float* __restrict__ W1, const float* __restrict__ b1,
    const float* __restrict__ W2, const float* __restrict__ b2,
    float* __restrict__ out) {
  const int b = blockIdx.x;
  const int j = threadIdx.x;          // 0..255, owns h[j]
  const int a = aspect[b];

  __shared__ float sx[EMB_DIM];
  sx[j] = x[(size_t)b * EMB_DIM + j];
  if (j < EMB_DIM - 256) sx[j + 256] = x[(size_t)b * EMB_DIM + j + 256];
  __syncthreads();

  const float* __restrict__ w1 = W1 + (size_t)a * EMB_DIM * HIDDEN + j;
  float h = b1[a * HIDDEN + j];
#pragma unroll 4
  for (int d = 0; d < EMB_DIM; ++d)
    h = fmaf(sx[d], w1[(size_t)d * HIDDEN], h);
  h = fmaxf(h, 0.f);

  const float* __restrict__ w2 = W2 + (size_t)a * HIDDEN * OUT_DIM + j * OUT_DIM;
  float p0 = h * w2[0];
  float p1 = h * w2[1];
  float p2 = h * w2[2];

  // 64-lane wave reduction
  for (int off = 32; off > 0; off >>= 1) {
    p0 += __shfl_down(p0, off);
    p1 += __shfl_down(p1, off);
    p2 += __shfl_down(p2, off);
  }

  __shared__ float part[4][OUT_DIM];
  const int wave = j >> 6;
  const int lane = j & 63;
  if (lane == 0) {
    part[wave][0] = p0;
    part[wave][1] = p1;
    part[wave][2] = p2;
  }
  __syncthreads();

  if (j < OUT_DIM) {
    float s = b2[a * OUT_DIM + j];
    for (int w = 0; w < 4; ++w) s += part[w][j];
    out[(size_t)b * OUT_DIM + j] = s;
  }
}

// ---------------------------------------------------------------------------
extern "C" void kernel_launch(void* const* d_in, const int* in_sizes, int n_in,
                              void* d_out, int out_size, void* d_ws, size_t ws_size,
                              hipStream_t stream) {
  const int*   ids    = (const int*)d_in[0];   // [B, SEQ]
  const int*   aspect = (const int*)d_in[1];   // [B]
  const float* emb    = (const float*)d_in[2]; // [VOCAB, EMB_DIM]
  const float* W1     = (const float*)d_in[3]; // [A, EMB_DIM, HIDDEN]
  const float* b1     = (const float*)d_in[4]; // [A, HIDDEN]
  const float* W2     = (const float*)d_in[5]; // [A, HIDDEN, OUT_DIM]
  const float* b2     = (const float*)d_in[6]; // [A, OUT_DIM]
  float*       out    = (float*)d_out;

  const int B = in_sizes[1];                   // 8192 samples
  float* x = (float*)d_ws;                     // [B, EMB_DIM] pooled, 9.8 MB

  pool_kernel<<<B, 256, 0, stream>>>(ids, emb, x);
  mlp_kernel<<<B, 256, 0, stream>>>(x, aspect, W1, b1, W2, b2, out);
}